// Round 3
// baseline (283.173 us; speedup 1.0000x reference)
//
#include <hip/hip_runtime.h>
#include <hip/hip_bf16.h>
#include <stdint.h>

// ---------------------------------------------------------------------------
// TensorNet: fused encoder MLP (128->256->256->256, relu) over 32x4096 tokens,
// per-batch mean -> p = relu(m^2) -> decoder MLP (256->512->512->10).
//
// R18: wave->token remap. Each wave owns 16 tokens x ALL 256 hidden (jt=16,
// tt=1) instead of 64 hidden x 64 tokens. All 4 waves load IDENTICAL a-frag
// addresses -> L1-shared (per-kc working set 16KB), block weight traffic
// 328KB -> 82KB (L2 671->170MB chip-wide), b-reads/wave 80 -> 20. Token-sum
// moves to a shfl_xor butterfly + 4KB scratch + coalesced 256-thread reduce.
//
// Explored & rejected (evidence in session log):
//  - MTILE=128 acc[4][8]: 2 blocks/CU, encoder 74-83us (R16).
//  - __launch_bounds__(256,4): VGPR forced down -> acc spills (R5).
//  - direct-global layer-1 B-frags + shfl reduce: 4x x-reads (R5/R6).
//  - manual a-frag ping-pong: compiler already schedules (R13).
//  - cooperative single-kernel: VGPR 176, coop+graph-capture fails (R11).
//  - decoder fused into encoder tail: encoder 67->140us (R14/R15).
// R17 wins kept: 32KB XOR-swizzled LDS (5 blocks/CU), bias-init acc,
// 128-block decoder, out pre-init'd to c3 by pack.
// ---------------------------------------------------------------------------

#define NIN   128
#define NHID  256
#define NDEC  512
#define NOUTC 10
#define BATCH 32
#define NTOK  4096
#define MTILE 64
#define NBLK  (BATCH * (NTOK / MTILE))   // 2048 encoder tiles

#define SWZ(t) (((t) & 7) << 4)          // XOR swizzle, bits 4-6

typedef short bf16x8 __attribute__((ext_vector_type(8)));
typedef float floatx4 __attribute__((ext_vector_type(4)));

__device__ __forceinline__ uint16_t f2b(float f) {
  union { uint32_t u; float f; } v; v.f = f;
  uint32_t r = v.u + 0x7FFFu + ((v.u >> 16) & 1u);   // RNE
  return (uint16_t)(r >> 16);
}
__device__ __forceinline__ uint32_t pkbf(float lo, float hi) {
  __hip_bfloat162 h = __float22bfloat162_rn(float2{lo, hi});  // v_cvt_pk_bf16_f32
  union { __hip_bfloat162 h; uint32_t u; } c; c.h = h;
  return c.u;
}

// ---------------------------------------------------------------------------
// Pack W1/W2/W3 (fp32 [K][256] row-major) into bf16 MFMA-A-fragment order.
// Also zero-inits msum and pre-loads out with c3 (decoder atomics accumulate
// on top; pack -> encoder -> decoder are stream-ordered).
// ---------------------------------------------------------------------------
__global__ __launch_bounds__(256) void pack_weights(
    const float* __restrict__ W1, const float* __restrict__ W2,
    const float* __restrict__ W3, const float* __restrict__ c3,
    uint16_t* __restrict__ pW, float* __restrict__ msum,
    float* __restrict__ out) {
  int p = blockIdx.x * blockDim.x + threadIdx.x;
  if (p < BATCH * NHID) msum[p] = 0.f;
  if (p < BATCH * NOUTC) out[p] = c3[p % NOUTC];
  const float* W; int K; int base;
  if (p < 32768)      { W = W1; K = NIN;  base = 0; }
  else if (p < 98304) { W = W2; K = NHID; base = 32768; p -= 32768; }
  else                { W = W3; K = NHID; base = 98304; p -= 98304; }
  int j    = p & 7;
  int ln   = (p >> 3) & 63;
  int rest = p >> 9;
  int KC = K >> 5;
  int kc = rest % KC;
  int mt = rest / KC;
  int m = mt * 16 + (ln & 15);
  int k = kc * 32 + ((ln >> 4) << 3) + j;
  pW[base + (((mt * KC + kc) * 64 + ln) << 3) + j] = f2b(W[k * NHID + m]);
}

// ---------------------------------------------------------------------------
// Fused encoder. Block = 256 thr (4 waves), 64 tokens. Wave w owns tokens
// [16w,16w+16) x all 256 hidden (16 jt-tiles). All waves read the SAME
// weight fragments per kc (L1-shared). LDS = 32768 B -> 5 blocks/CU.
// ---------------------------------------------------------------------------
__global__ __launch_bounds__(256) void encoder(
    const float* __restrict__ x,        // [BATCH*NTOK][NIN] fp32
    const uint16_t* __restrict__ pW,
    const float* __restrict__ b1,
    const float* __restrict__ b2,
    const float* __restrict__ b3,
    float* __restrict__ msum) {         // [BATCH][NHID] fp32 accum
  __shared__ __align__(16) uint8_t Hs[MTILE * 512];   // 32768 B

  const int tid  = threadIdx.x;
  const int wave = tid >> 6;
  const int lane = tid & 63;
  const int l15  = lane & 15;
  const int q    = lane >> 4;
  const int tok0  = blockIdx.x * MTILE;
  const int batch = blockIdx.x >> 6;          // 64 tiles per batch
  const int trow  = wave * 16 + l15;          // this lane's token row

  const uint16_t* pW1 = pW;             // KC=4
  const uint16_t* pW2 = pW + 32768;     // KC=8
  const uint16_t* pW3 = pW + 98304;     // KC=8

  // ---- stage x tile: 64 tokens x 128 ch fp32 -> bf16, row stride 256B ----
  {
    const float4* xv = (const float4*)(x + (size_t)tok0 * NIN);
#pragma unroll
    for (int i = 0; i < 4; ++i) {
      const int u = tid + i * 256;            // 8-float unit, 0..1023
      float4 va = xv[2 * u];
      float4 vb = xv[2 * u + 1];
      uint4 w = make_uint4(pkbf(va.x, va.y), pkbf(va.z, va.w),
                           pkbf(vb.x, vb.y), pkbf(vb.z, vb.w));
      const int row = u >> 4;                 // token 0..63
      const int cb  = (u & 15) << 4;          // byte col 0..240
      *(uint4*)&Hs[row * 256 + (cb ^ SWZ(row))] = w;
    }
  }
  __syncthreads();

  floatx4 acc[16];   // [jt]; col = token (l15), rows = jt*16 + q*4 + r

  // ---- layer 1: K = 128, A = W1^T, B = x; acc init = bias ----
#pragma unroll
  for (int jt = 0; jt < 16; ++jt) {
    const float4 bb = *(const float4*)&b1[jt * 16 + q * 4];
    acc[jt] = (floatx4){bb.x, bb.y, bb.z, bb.w};
  }
#pragma unroll
  for (int kc = 0; kc < 4; ++kc) {
    bf16x8 b = *(const bf16x8*)&Hs[trow * 256 + ((kc * 64 + q * 16) ^ SWZ(trow))];
#pragma unroll
    for (int jc = 0; jc < 4; ++jc) {
      bf16x8 a0 = *(const bf16x8*)(pW1 + ((((jc * 4 + 0) * 4 + kc) * 64 + lane) << 3));
      bf16x8 a1 = *(const bf16x8*)(pW1 + ((((jc * 4 + 1) * 4 + kc) * 64 + lane) << 3));
      bf16x8 a2 = *(const bf16x8*)(pW1 + ((((jc * 4 + 2) * 4 + kc) * 64 + lane) << 3));
      bf16x8 a3 = *(const bf16x8*)(pW1 + ((((jc * 4 + 3) * 4 + kc) * 64 + lane) << 3));
      acc[jc * 4 + 0] = __builtin_amdgcn_mfma_f32_16x16x32_bf16(a0, b, acc[jc * 4 + 0], 0, 0, 0);
      acc[jc * 4 + 1] = __builtin_amdgcn_mfma_f32_16x16x32_bf16(a1, b, acc[jc * 4 + 1], 0, 0, 0);
      acc[jc * 4 + 2] = __builtin_amdgcn_mfma_f32_16x16x32_bf16(a2, b, acc[jc * 4 + 2], 0, 0, 0);
      acc[jc * 4 + 3] = __builtin_amdgcn_mfma_f32_16x16x32_bf16(a3, b, acc[jc * 4 + 3], 0, 0, 0);
    }
  }
  __syncthreads();   // x reads done before h1 overwrites

#pragma unroll
  for (int jt = 0; jt < 16; ++jt) {
    const int cb = jt * 32 + q * 8;
    float v0 = fmaxf(acc[jt][0], 0.f);
    float v1 = fmaxf(acc[jt][1], 0.f);
    float v2 = fmaxf(acc[jt][2], 0.f);
    float v3 = fmaxf(acc[jt][3], 0.f);
    *(uint2*)&Hs[trow * 512 + (cb ^ SWZ(trow))] = make_uint2(pkbf(v0, v1), pkbf(v2, v3));
  }
  __syncthreads();

  // ---- layer 2: K = 256, A = W2^T, B = h1 ----
#pragma unroll
  for (int jt = 0; jt < 16; ++jt) {
    const float4 bb = *(const float4*)&b2[jt * 16 + q * 4];
    acc[jt] = (floatx4){bb.x, bb.y, bb.z, bb.w};
  }
#pragma unroll
  for (int kc = 0; kc < 8; ++kc) {
    bf16x8 b = *(const bf16x8*)&Hs[trow * 512 + ((kc * 64 + q * 16) ^ SWZ(trow))];
#pragma unroll
    for (int jc = 0; jc < 4; ++jc) {
      bf16x8 a0 = *(const bf16x8*)(pW2 + ((((jc * 4 + 0) * 8 + kc) * 64 + lane) << 3));
      bf16x8 a1 = *(const bf16x8*)(pW2 + ((((jc * 4 + 1) * 8 + kc) * 64 + lane) << 3));
      bf16x8 a2 = *(const bf16x8*)(pW2 + ((((jc * 4 + 2) * 8 + kc) * 64 + lane) << 3));
      bf16x8 a3 = *(const bf16x8*)(pW2 + ((((jc * 4 + 3) * 8 + kc) * 64 + lane) << 3));
      acc[jc * 4 + 0] = __builtin_amdgcn_mfma_f32_16x16x32_bf16(a0, b, acc[jc * 4 + 0], 0, 0, 0);
      acc[jc * 4 + 1] = __builtin_amdgcn_mfma_f32_16x16x32_bf16(a1, b, acc[jc * 4 + 1], 0, 0, 0);
      acc[jc * 4 + 2] = __builtin_amdgcn_mfma_f32_16x16x32_bf16(a2, b, acc[jc * 4 + 2], 0, 0, 0);
      acc[jc * 4 + 3] = __builtin_amdgcn_mfma_f32_16x16x32_bf16(a3, b, acc[jc * 4 + 3], 0, 0, 0);
    }
  }
  __syncthreads();   // h1 reads done before overwrite
#pragma unroll
  for (int jt = 0; jt < 16; ++jt) {
    const int cb = jt * 32 + q * 8;
    float v0 = fmaxf(acc[jt][0], 0.f);
    float v1 = fmaxf(acc[jt][1], 0.f);
    float v2 = fmaxf(acc[jt][2], 0.f);
    float v3 = fmaxf(acc[jt][3], 0.f);
    *(uint2*)&Hs[trow * 512 + (cb ^ SWZ(trow))] = make_uint2(pkbf(v0, v1), pkbf(v2, v3));
  }
  __syncthreads();

  // ---- layer 3: K = 256, A = W3^T, B = h2, fused token-sum ----
#pragma unroll
  for (int jt = 0; jt < 16; ++jt) {
    const float4 bb = *(const float4*)&b3[jt * 16 + q * 4];
    acc[jt] = (floatx4){bb.x, bb.y, bb.z, bb.w};
  }
#pragma unroll
  for (int kc = 0; kc < 8; ++kc) {
    bf16x8 b = *(const bf16x8*)&Hs[trow * 512 + ((kc * 64 + q * 16) ^ SWZ(trow))];
#pragma unroll
    for (int jc = 0; jc < 4; ++jc) {
      bf16x8 a0 = *(const bf16x8*)(pW3 + ((((jc * 4 + 0) * 8 + kc) * 64 + lane) << 3));
      bf16x8 a1 = *(const bf16x8*)(pW3 + ((((jc * 4 + 1) * 8 + kc) * 64 + lane) << 3));
      bf16x8 a2 = *(const bf16x8*)(pW3 + ((((jc * 4 + 2) * 8 + kc) * 64 + lane) << 3));
      bf16x8 a3 = *(const bf16x8*)(pW3 + ((((jc * 4 + 3) * 8 + kc) * 64 + lane) << 3));
      acc[jc * 4 + 0] = __builtin_amdgcn_mfma_f32_16x16x32_bf16(a0, b, acc[jc * 4 + 0], 0, 0, 0);
      acc[jc * 4 + 1] = __builtin_amdgcn_mfma_f32_16x16x32_bf16(a1, b, acc[jc * 4 + 1], 0, 0, 0);
      acc[jc * 4 + 2] = __builtin_amdgcn_mfma_f32_16x16x32_bf16(a2, b, acc[jc * 4 + 2], 0, 0, 0);
      acc[jc * 4 + 3] = __builtin_amdgcn_mfma_f32_16x16x32_bf16(a3, b, acc[jc * 4 + 3], 0, 0, 0);
    }
  }

  // relu + token-sum via shfl_xor butterfly over the 16 token lanes (l15).
  // Register-only -> runs before the barrier, overlapping other waves.
  float4 jsum[16];
#pragma unroll
  for (int jt = 0; jt < 16; ++jt) {
    float s0 = fmaxf(acc[jt][0], 0.f);
    float s1 = fmaxf(acc[jt][1], 0.f);
    float s2 = fmaxf(acc[jt][2], 0.f);
    float s3 = fmaxf(acc[jt][3], 0.f);
#pragma unroll
    for (int m = 1; m <= 8; m <<= 1) {
      s0 += __shfl_xor(s0, m);
      s1 += __shfl_xor(s1, m);
      s2 += __shfl_xor(s2, m);
      s3 += __shfl_xor(s3, m);
    }
    jsum[jt] = (float4){s0, s1, s2, s3};
  }
  __syncthreads();   // h2 reads done before scratch overwrites Hs

  // scratch: float4 per (wave, jt, q) = 256 entries = 4KB.
  {
    float4* scratch = (float4*)Hs;
#pragma unroll
    for (int jt = 0; jt < 16; ++jt)
      if (l15 == jt)
        scratch[(wave * 16 + jt) * 4 + q] = jsum[jt];
  }
  __syncthreads();
  if (tid < NHID) {
    const float* sf = (const float*)Hs;
    float v = sf[tid] + sf[256 + tid] + sf[512 + tid] + sf[768 + tid];
    atomicAdd(&msum[batch * NHID + tid], v);
  }
}

// ---------------------------------------------------------------------------
// Decoder: 128 blocks = (batch x d2-quarter), 1024 threads. Each block
// computes the full d1 (redundant x4, D1 is L2-resident), its 128-wide d2
// quarter, and atomicAdds its partial L3 dot into out (pre-init'd to c3).
// ---------------------------------------------------------------------------
__global__ __launch_bounds__(1024) void decoder(
    const float* __restrict__ msum,
    const float* __restrict__ D1, const float* __restrict__ c1,
    const float* __restrict__ D2, const float* __restrict__ c2,
    const float* __restrict__ D3,
    float* __restrict__ out) {
  __shared__ float p[NHID];
  __shared__ float d1[NDEC];
  __shared__ float d2q[128];
  __shared__ __align__(16) float red[4096];   // 16 KB
  const int b = blockIdx.x >> 2, qd = blockIdx.x & 3, t = threadIdx.x;

  if (t < NHID) {
    float m = msum[b * NHID + t] * (1.f / NTOK);
    p[t] = m * m;                        // relu(m^2) == m^2
  }
  __syncthreads();

  // ---- layer 1 (full, redundant x4): K = 256 -> 32 k per split ----
  {
    const int jg = t & 127;              // j-group of 4
    const int ks = t >> 7;               // 0..7 K-split
    const float4* D1v = (const float4*)D1;   // [256][128] float4
    float4 s = {0.f, 0.f, 0.f, 0.f};
    for (int k = ks * 32; k < ks * 32 + 32; ++k) {
      float4 w = D1v[k * 128 + jg];
      float pv = p[k];
      s.x += pv * w.x; s.y += pv * w.y; s.z += pv * w.z; s.w += pv * w.w;
    }
    *(float4*)&red[t * 4] = s;
    __syncthreads();
    if (t < NDEC) {
      float v = c1[t];
#pragma unroll
      for (int i = 0; i < 8; ++i) v += red[i * 512 + t];
      d1[t] = fmaxf(v, 0.f);
    }
    __syncthreads();
  }

  // ---- layer 2 (quarter): 128 outs, K = 512 -> 32 splits x 16 k ----
  {
    const int jg2 = t & 31;              // float4 group within quarter
    const int ks2 = t >> 5;              // 0..31 K-split
    const float4* D2v = (const float4*)D2;   // [512][128] float4
    float4 s = {0.f, 0.f, 0.f, 0.f};
    for (int k = ks2 * 16; k < ks2 * 16 + 16; ++k) {
      float4 w = D2v[k * 128 + qd * 32 + jg2];
      float hv = d1[k];
      s.x += hv * w.x; s.y += hv * w.y; s.z += hv * w.z; s.w += hv * w.w;
    }
    *(float4*)&red[t * 4] = s;           // == red[ks2*128 + jg2*4 + c]
    __syncthreads();
    if (t < 128) {
      float v = c2[qd * 128 + t];
#pragma unroll
      for (int i = 0; i < 32; ++i) v += red[i * 128 + t];
      d2q[t] = fmaxf(v, 0.f);
    }
    __syncthreads();
  }

  // ---- layer 3 partial: quarter K = 128; 64 k-chunks x 16 j-slots ----
  {
    const int j3 = t & 15;
    const int kc = t >> 4;               // 0..63, 2 k's each
    float s = 0.f;
    if (j3 < NOUTC)
      for (int k = kc * 2; k < kc * 2 + 2; ++k)
        s += d2q[k] * D3[(qd * 128 + k) * NOUTC + j3];
    red[t] = s;
    __syncthreads();
    if (t < NOUTC) {
      float v = 0.f;
#pragma unroll
      for (int i = 0; i < 64; ++i) v += red[i * 16 + t];
      atomicAdd(&out[b * NOUTC + t], v);
    }
  }
}

// ---------------------------------------------------------------------------
extern "C" void kernel_launch(void* const* d_in, const int* in_sizes, int n_in,
                              void* d_out, int out_size, void* d_ws, size_t ws_size,
                              hipStream_t stream) {
  const float* x  = (const float*)d_in[0];
  const float* W1 = (const float*)d_in[1];
  const float* b1 = (const float*)d_in[2];
  const float* W2 = (const float*)d_in[3];
  const float* b2 = (const float*)d_in[4];
  const float* W3 = (const float*)d_in[5];
  const float* b3 = (const float*)d_in[6];
  const float* D1 = (const float*)d_in[7];
  const float* c1 = (const float*)d_in[8];
  const float* D2 = (const float*)d_in[9];
  const float* c2 = (const float*)d_in[10];
  const float* D3 = (const float*)d_in[11];
  const float* c3 = (const float*)d_in[12];

  // ws: [0,320K) packed bf16 W | [384K,416K) msum
  uint16_t* pW   = (uint16_t*)d_ws;
  float*    msum = (float*)((char*)d_ws + 384 * 1024);

  pack_weights<<<640, 256, 0, stream>>>(W1, W2, W3, c3, pW, msum,
                                        (float*)d_out);
  encoder<<<NBLK, 256, 0, stream>>>(x, pW, b1, b2, b3, msum);
  decoder<<<128, 1024, 0, stream>>>(msum, D1, c1, D2, c2, D3,
                                    (float*)d_out);
}